// Round 23
// baseline (66.138 us; speedup 1.0000x reference)
//
#include <hip/hip_runtime.h>

#define B_ 64
#define N_ 2048
#define J_ 32
#define D_ 128
#define NEG_SLOPE_ 0.2f

typedef __attribute__((ext_vector_type(4))) float f32x4;
typedef __attribute__((ext_vector_type(8))) __bf16 bf16x8;
typedef __attribute__((ext_vector_type(4))) __bf16 bf16x4;

#define ACT_NONE 0
#define ACT_ELU 1
#define ACT_LEAKY 2

template<int ACT>
__device__ __forceinline__ float apply_act(float v) {
    if constexpr (ACT == ACT_ELU)        return v > 0.f ? v : __expf(v) - 1.f;
    else if constexpr (ACT == ACT_LEAKY) return v >= 0.f ? v : NEG_SLOPE_ * v;
    else return v;
}

// read one bf16x8 fragment from swizzled row-major [row][128] storage
__device__ __forceinline__ bf16x8 frag_ld(const __bf16* src, int row, int kc) {
    return *(const bf16x8*)&src[row * D_ + ((kc ^ (row & 7)) << 3)];
}

// preload this wave's 16-col W^T strip into registers: 4 frags (16 VGPR)
__device__ __forceinline__ void load_wregs1(const __bf16* __restrict__ wmat,
                                            int wst, int ln, int lq, bf16x8 wr_[4]) {
#pragma unroll
    for (int ks = 0; ks < 4; ++ks)
        wr_[ks] = frag_ld(wmat, wst * 16 + ln, ks * 4 + lq);
}

// convert float4 pair -> bf16x8, store swizzled (no scale: pure convert-copy)
__device__ __forceinline__ void st_row(__bf16* dst, int row, int ch,
                                       float4 f0, float4 f1) {
    bf16x8 u;
    u[0] = (__bf16)f0.x; u[1] = (__bf16)f0.y; u[2] = (__bf16)f0.z; u[3] = (__bf16)f0.w;
    u[4] = (__bf16)f1.x; u[5] = (__bf16)f1.y; u[6] = (__bf16)f1.z; u[7] = (__bf16)f1.w;
    *(bf16x8*)&dst[row * D_ + ((ch ^ (row & 7)) << 3)] = u;
}

// 64-row strip GEMM (16-col strip): lane -> out[row nt*16+(l&15)][cols wst*16+lq*4 ..+3]
__device__ __forceinline__ void gemmS64(const __bf16* xb, const bf16x8 wr_[4],
                                        int ln, int lq, f32x4 acc[4]) {
    const f32x4 z = {0.f, 0.f, 0.f, 0.f};
#pragma unroll
    for (int nt = 0; nt < 4; ++nt) acc[nt] = z;
#pragma unroll
    for (int ks = 0; ks < 4; ++ks) {
        const int kc = ks * 4 + lq;
#pragma unroll
        for (int nt = 0; nt < 4; ++nt) {
            const bf16x8 b = frag_ld(xb, nt * 16 + ln, kc);
            acc[nt] = __builtin_amdgcn_mfma_f32_16x16x32_bf16(wr_[ks], b, acc[nt], 0, 0, 0);
        }
    }
}

// 32-row strip GEMM; INIT zeroes acc
template<bool INIT>
__device__ __forceinline__ void gemmS32(const __bf16* xb, const bf16x8 wr_[4],
                                        int ln, int lq, f32x4 acc[2]) {
    if constexpr (INIT) {
        const f32x4 z = {0.f, 0.f, 0.f, 0.f};
        acc[0] = z; acc[1] = z;
    }
#pragma unroll
    for (int ks = 0; ks < 4; ++ks) {
        const int kc = ks * 4 + lq;
        const bf16x8 b0 = frag_ld(xb, ln, kc);
        const bf16x8 b1 = frag_ld(xb, 16 + ln, kc);
        acc[0] = __builtin_amdgcn_mfma_f32_16x16x32_bf16(wr_[ks], b0, acc[0], 0, 0, 0);
        acc[1] = __builtin_amdgcn_mfma_f32_16x16x32_bf16(wr_[ks], b1, acc[1], 0, 0, 0);
    }
}

// fw1 epilogue: h = elu(scale_row * acc + b1) -> swizzled LDS (scale: 1 for rows 0-31,
// rsc for rows 32-63 -- the r^k fold moved from staging to here by GEMM linearity)
__device__ __forceinline__ void epiS64_fw1(const f32x4 acc[4], __bf16* dst,
                                           const float* __restrict__ bias,
                                           float rscA, float rscB,
                                           int wst, int ln, int lq) {
    const int cb = wst * 16 + lq * 4;
    const f32x4 bv = *(const f32x4*)&bias[cb];
#pragma unroll
    for (int nt = 0; nt < 4; ++nt) {
        const float sc = (nt < 2) ? 1.f : ((nt == 2) ? rscA : rscB);
        const int jr = nt * 16 + ln;
        bf16x4 o;
#pragma unroll
        for (int r = 0; r < 4; ++r)
            o[r] = (__bf16)apply_act<ACT_ELU>(sc * acc[nt][r] + bv[r]);
        *(bf16x4*)&dst[jr * D_ + (((cb >> 3) ^ (jr & 7)) << 3) + (cb & 7)] = o;
    }
}

// 32-row epilogue -> swizzled LDS at row offset
template<int ACT>
__device__ __forceinline__ void epiS32_lds(const f32x4 acc[2], __bf16* dst, int rowoff,
                                           const float* __restrict__ bias,
                                           int wst, int ln, int lq) {
    const int cb = wst * 16 + lq * 4;
    const f32x4 bv = *(const f32x4*)&bias[cb];
#pragma unroll
    for (int nt = 0; nt < 2; ++nt) {
        const int jr = rowoff + nt * 16 + ln;
        bf16x4 o;
#pragma unroll
        for (int r = 0; r < 4; ++r)
            o[r] = (__bf16)apply_act<ACT>(acc[nt][r] + bv[r]);
        *(bf16x4*)&dst[jr * D_ + (((cb >> 3) ^ (jr & 7)) << 3) + (cb & 7)] = o;
    }
}

// prep: blocks 0-5 convert W fp32 -> WT bf16 swizzled; blocks 6-69 Sbuf + nvalid
__global__ __launch_bounds__(256) void k_prep(
    const float* __restrict__ w0, const float* __restrict__ w1,
    const float* __restrict__ w2, const float* __restrict__ w3,
    const float* __restrict__ w4, const float* __restrict__ w5,
    __bf16* __restrict__ wdst,
    const float* __restrict__ F, const int* __restrict__ STEP,
    const int* __restrict__ ENDB, const int* __restrict__ BIDX,
    float* __restrict__ Sbuf, int* __restrict__ nvalid) {
    const int t = threadIdx.x;
    if (blockIdx.x < 6) {
        const float* src;
        switch (blockIdx.x) {
            case 0: src = w0; break; case 1: src = w1; break; case 2: src = w2; break;
            case 3: src = w3; break; case 4: src = w4; break; default: src = w5; break;
        }
        __bf16* d = wdst + (size_t)blockIdx.x * D_ * D_;
        for (int id = t; id < D_ * 16; id += 256) {
            const int n = id >> 4, ch = id & 15;
            bf16x8 u;
#pragma unroll
            for (int j = 0; j < 8; ++j) u[j] = (__bf16)src[(ch * 8 + j) * D_ + n];
            *(bf16x8*)&d[n * D_ + ((ch ^ (n & 7)) << 3)] = u;
        }
        return;
    }
    const int b = blockIdx.x - 6;
    __shared__ int steps_s[J_];
    __shared__ int valid_s[J_];
    __shared__ int nv;
    const int bi = BIDX[b];
    if (t == 0) nv = 0;
    __syncthreads();
    if (t < J_) {
        const int s = STEP[bi * J_ + t];
        const int e = ENDB[bi * J_ + t];
        steps_s[t] = s;
        const int v = (s <= e) ? 1 : 0;
        valid_s[t] = v;
        if (v) atomicAdd(&nv, 1);
    }
    __syncthreads();
    if (t < D_) {
        float acc = 0.f;
        for (int j = 0; j < J_; ++j)
            if (valid_s[j]) acc += F[((size_t)b * N_ + steps_s[j]) * D_ + t];
        Sbuf[b * D_ + t] = acc;
    }
    if (t == 0) nvalid[b] = nv;
}

// fully fused, 32-output-row blocks, 512 threads (8 waves x 16-col strips), 32 KB LDS.
// Staging is unconditional + predicate-free (r^k folded into fw1 epilogue).
__global__ __launch_bounds__(512, 4) void k_fused(
    const float* __restrict__ F, const float* __restrict__ rp_,
    const __bf16* __restrict__ wsW,
    const float* __restrict__ fb1, const float* __restrict__ fb2,
    const float* __restrict__ zb1, const float* __restrict__ zb2,
    const float* __restrict__ pb1, const float* __restrict__ pb2,
    const int* __restrict__ STEP, const int* __restrict__ ENDB,
    const int* __restrict__ BIDX, const float* __restrict__ Sbuf,
    const int* __restrict__ nvalid, float* __restrict__ out) {
    __shared__ __bf16 xs[64 * D_];   // rows 0-31: x -> cand/z (predicated); rows 32-63: xprev (raw)
    __shared__ __bf16 hs[64 * D_];   // fw h; head: mixed/zh; pr: h'

    const int t = threadIdx.x;
    const int lane = t & 63, wst = t >> 6;        // wst 0..7, 16-col strip
    const int ln = lane & 15, lq = lane >> 4;
    const int bid = blockIdx.x;
    const int b = bid >> 6, ti = bid & 63;
    const int r0 = ti * 32;

    // ---- stage loads: issue IMMEDIATELY (no dependency on STEP/ENDB) ----
    const float* Fb = F + (size_t)b * N_ * D_;
    const int rr_ = t >> 4;            // 0..31
    const int ch_ = t & 15;
    const int rA = r0 + rr_;
    const float* qA = Fb + (size_t)rA * D_ + ch_ * 8;
    const float4 xa0 = *(const float4*)qA, xa1 = *(const float4*)(qA + 4);
    const int rP = (rA > 0) ? rA - 1 : 0;          // clamped; row 0 never updated
    const float* qP = Fb + (size_t)rP * D_ + ch_ * 8;
    const float4 ya0 = *(const float4*)qP, ya1 = *(const float4*)(qP + 4);

    const int bi = BIDX[b];
    const int jb = ti >> 1;                        // the single job covering rows [r0, r0+31]
    const int s_j = STEP[bi * J_ + jb];
    const int e_j = ENDB[bi * J_ + jb];
    const float r = *rp_;
    const float l2r = __log2f(r);
    const int lo = (s_j + 1 > r0) ? s_j + 1 : r0;
    const int hi = (e_j < r0 + 31) ? e_j : r0 + 31;
    const bool has_upd = lo <= hi;
    const bool head_tile = (ti == 0);

    // prefetch first W strip: fw W1 (has_upd) else pr P1
    bf16x8 wA[4];
    load_wregs1(has_upd ? wsW : wsW + 2 * 16384, wst, ln, lq, wA);

    st_row(xs, rr_, ch_, xa0, xa1);
    st_row(xs, rr_ + 32, ch_, ya0, ya1);
    __syncthreads();                         // (1) staging visible

    if (has_upd) {
        // fw layer 1: one 64-row GEMM -> hs with per-row r^k scale in epilogue
        f32x4 acc[4];
        gemmS64(xs, wA, ln, lq, acc);
        bf16x8 wB[4];
        load_wregs1(wsW + 16384, wst, ln, lq, wB);    // fw W2^T strip (in flight)
        // rsc for h rows 32+ln (out row r0+ln) and 48+ln (out row r0+16+ln)
        const int iA = r0 + ln, iB = r0 + 16 + ln;
        const bool uA = (iA > s_j) && (iA <= e_j);
        const bool uB = (iB > s_j) && (iB <= e_j);
        const float rscA = uA ? exp2f((float)(iA - s_j) * l2r) : 0.f;
        const float rscB = uB ? exp2f((float)(iB - s_j) * l2r) : 0.f;
        epiS64_fw1(acc, hs, fb1, rscA, rscB, wst, ln, lq);
        __syncthreads();                     // (2) h visible
        // fw layer 2: chain both h halves -> cand, predicated into xs rows 0-31
        f32x4 a2[2];
        gemmS32<true>(hs, wB, ln, lq, a2);
        gemmS32<false>(hs + 32 * D_, wB, ln, lq, a2);
        const int cb = wst * 16 + lq * 4;
        const f32x4 bv = *(const f32x4*)&fb2[cb];
#pragma unroll
        for (int nt = 0; nt < 2; ++nt) {
            const int row = nt * 16 + ln;
            const int i = r0 + row;
            if (!((i > s_j) && (i <= e_j))) continue;
            bf16x4 o;
#pragma unroll
            for (int rr2 = 0; rr2 < 4; ++rr2)
                o[rr2] = (__bf16)(a2[nt][rr2] + 2.f * bv[rr2]);
            *(bf16x4*)&xs[row * D_ + (((cb >> 3) ^ (row & 7)) << 3) + (cb & 7)] = o;
        }
    }

    // head path (tile 0 of each batch): z = MLP_zj(mixed) -> xs rows 0-31 (valid jobs)
    if (head_tile) {
        __syncthreads();                     // fw2 hs reads + cand xs writes done
        const float n_ = (float)nvalid[b];
        const float inv = (n_ > 0.f) ? 1.f / n_ : 0.f;
        {
            const int row = t >> 4, ch = t & 15;  // 512 = 32 rows x 16 chunks
            const int sr = STEP[bi * J_ + row];
            const float* cr = Fb + (size_t)sr * D_ + ch * 8;
            const float4 c0 = *(const float4*)cr, c1 = *(const float4*)(cr + 4);
            const float4 s0 = *(const float4*)(Sbuf + b * D_ + ch * 8);
            const float4 s1 = *(const float4*)(Sbuf + b * D_ + ch * 8 + 4);
            bf16x8 u;
            u[0] = (__bf16)((c0.x + r * (s0.x - c0.x)) * inv);
            u[1] = (__bf16)((c0.y + r * (s0.y - c0.y)) * inv);
            u[2] = (__bf16)((c0.z + r * (s0.z - c0.z)) * inv);
            u[3] = (__bf16)((c0.w + r * (s0.w - c0.w)) * inv);
            u[4] = (__bf16)((c1.x + r * (s1.x - c1.x)) * inv);
            u[5] = (__bf16)((c1.y + r * (s1.y - c1.y)) * inv);
            u[6] = (__bf16)((c1.z + r * (s1.z - c1.z)) * inv);
            u[7] = (__bf16)((c1.w + r * (s1.w - c1.w)) * inv);
            *(bf16x8*)&hs[row * D_ + ((ch ^ (row & 7)) << 3)] = u;
        }
        __syncthreads();                     // mixed visible
        {
            bf16x8 wza[4];
            load_wregs1(wsW + 4 * 16384, wst, ln, lq, wza);
            f32x4 az[2];
            gemmS32<true>(hs, wza, ln, lq, az);                 // reads hs rows 0-31
            epiS32_lds<ACT_ELU>(az, hs, 32, zb1, wst, ln, lq);  // writes rows 32-63 (disjoint)
        }
        __syncthreads();                     // zh visible
        {
            bf16x8 wzb[4];
            load_wregs1(wsW + 5 * 16384, wst, ln, lq, wzb);
            f32x4 az[2];
            gemmS32<true>(hs + 32 * D_, wzb, ln, lq, az);
            const int cb = wst * 16 + lq * 4;
            const f32x4 bv = *(const f32x4*)&zb2[cb];
#pragma unroll
            for (int nt = 0; nt < 2; ++nt) {
                const int row = nt * 16 + ln;
                const int sr = STEP[bi * J_ + row];
                const int er = ENDB[bi * J_ + row];
                if (sr > er) continue;       // invalid job -> keep x/cand
                bf16x4 o;
#pragma unroll
                for (int rr2 = 0; rr2 < 4; ++rr2)
                    o[rr2] = (__bf16)(az[nt][rr2] + bv[rr2]);
                *(bf16x4*)&xs[row * D_ + (((cb >> 3) ^ (row & 7)) << 3) + (cb & 7)] = o;
            }
        }
    }

    // For tiles that ran fw/head: reload wA <- pr P1 and fence xs writes.
    // Pure passthrough tiles skip both (xs untouched since staging barrier).
    if (has_upd || head_tile) {
        load_wregs1(wsW + 2 * 16384, wst, ln, lq, wA);
        __syncthreads();                     // xs final (x/cand/z); hs free
    }

    // pr layer 1: xs rows 0-31 -> h' -> hs rows 0-31; P2 prefetch under epi
    f32x4 ap[2];
    gemmS32<true>(xs, wA, ln, lq, ap);
    bf16x8 wB2[4];
    load_wregs1(wsW + 3 * 16384, wst, ln, lq, wB2);   // pr P2^T strip (in flight)
    epiS32_lds<ACT_ELU>(ap, hs, 0, pb1, wst, ln, lq);
    __syncthreads();                         // h' visible

    // pr layer 2: hs rows 0-31 -> out
    gemmS32<true>(hs, wB2, ln, lq, ap);
    float* outb = out + ((size_t)b * N_ + r0) * D_;
    const int cb = wst * 16 + lq * 4;
    const f32x4 bv = *(const f32x4*)&pb2[cb];
#pragma unroll
    for (int nt = 0; nt < 2; ++nt) {
        const int jr = nt * 16 + ln;
        f32x4 o;
#pragma unroll
        for (int rr2 = 0; rr2 < 4; ++rr2)
            o[rr2] = apply_act<ACT_LEAKY>(ap[nt][rr2] + bv[rr2]);
        *(f32x4*)&outb[(size_t)jr * D_ + cb] = o;
    }
}

extern "C" void kernel_launch(void* const* d_in, const int* in_sizes, int n_in,
                              void* d_out, int out_size, void* d_ws, size_t ws_size,
                              hipStream_t stream) {
    const float* F    = (const float*)d_in[0];
    const float* rp   = (const float*)d_in[1];
    const int*  STEP  = (const int*)d_in[2];
    const int*  ENDB  = (const int*)d_in[3];
    const int*  BIDX  = (const int*)d_in[5];
    const float* fwW1 = (const float*)d_in[6];
    const float* fwb1 = (const float*)d_in[7];
    const float* fwW2 = (const float*)d_in[8];
    const float* fwb2 = (const float*)d_in[9];
    const float* zjW1 = (const float*)d_in[10];
    const float* zjb1 = (const float*)d_in[11];
    const float* zjW2 = (const float*)d_in[12];
    const float* zjb2 = (const float*)d_in[13];
    const float* prW1 = (const float*)d_in[14];
    const float* prb1 = (const float*)d_in[15];
    const float* prW2 = (const float*)d_in[16];
    const float* prb2 = (const float*)d_in[17];
    float* out = (float*)d_out;

    char* ws = (char*)d_ws;
    __bf16* wsW = (__bf16*)ws;                 // 393216 B
    float* Sbuf = (float*)(ws + 393216);       // 32768 B
    int* nvalid = (int*)(ws + 425984);         // 256 B

    hipLaunchKernelGGL(k_prep, dim3(70), dim3(256), 0, stream,
                       fwW1, fwW2, prW1, prW2, zjW1, zjW2, wsW,
                       F, STEP, ENDB, BIDX, Sbuf, nvalid);
    hipLaunchKernelGGL(k_fused, dim3(B_ * 64), dim3(512), 0, stream,
                       F, rp, wsW, fwb1, fwb2, zjb1, zjb2, prb1, prb2,
                       STEP, ENDB, BIDX, Sbuf, nvalid, out);
}

// Round 24
// 61.366 us; speedup vs baseline: 1.0778x; 1.0778x over previous
//
#include <hip/hip_runtime.h>

#define B_ 64
#define N_ 2048
#define J_ 32
#define D_ 128
#define NEG_SLOPE_ 0.2f

typedef __attribute__((ext_vector_type(4))) float f32x4;
typedef __attribute__((ext_vector_type(8))) __bf16 bf16x8;
typedef __attribute__((ext_vector_type(4))) __bf16 bf16x4;

#define ACT_NONE 0
#define ACT_ELU 1
#define ACT_LEAKY 2

template<int ACT>
__device__ __forceinline__ float apply_act(float v) {
    if constexpr (ACT == ACT_ELU)        return v > 0.f ? v : __expf(v) - 1.f;
    else if constexpr (ACT == ACT_LEAKY) return v >= 0.f ? v : NEG_SLOPE_ * v;
    else return v;
}

// read one bf16x8 fragment from swizzled row-major [row][128] storage
__device__ __forceinline__ bf16x8 frag_ld(const __bf16* src, int row, int kc) {
    return *(const bf16x8*)&src[row * D_ + ((kc ^ (row & 7)) << 3)];
}

// preload this wave's 16-col W^T strip into registers: 4 frags (16 VGPR)
__device__ __forceinline__ void load_wregs1(const __bf16* __restrict__ wmat,
                                            int wst, int ln, int lq, bf16x8 wr_[4]) {
#pragma unroll
    for (int ks = 0; ks < 4; ++ks)
        wr_[ks] = frag_ld(wmat, wst * 16 + ln, ks * 4 + lq);
}

// convert float4 pair -> scaled bf16x8, store swizzled
__device__ __forceinline__ void st_row(__bf16* dst, int row, int ch,
                                       float4 f0, float4 f1, float s) {
    bf16x8 u;
    u[0] = (__bf16)(f0.x * s); u[1] = (__bf16)(f0.y * s);
    u[2] = (__bf16)(f0.z * s); u[3] = (__bf16)(f0.w * s);
    u[4] = (__bf16)(f1.x * s); u[5] = (__bf16)(f1.y * s);
    u[6] = (__bf16)(f1.z * s); u[7] = (__bf16)(f1.w * s);
    *(bf16x8*)&dst[row * D_ + ((ch ^ (row & 7)) << 3)] = u;
}

// 64-row strip GEMM (16-col strip): lane -> out[row nt*16+(l&15)][cols wst*16+lq*4 ..+3]
__device__ __forceinline__ void gemmS64(const __bf16* xb, const bf16x8 wr_[4],
                                        int ln, int lq, f32x4 acc[4]) {
    const f32x4 z = {0.f, 0.f, 0.f, 0.f};
#pragma unroll
    for (int nt = 0; nt < 4; ++nt) acc[nt] = z;
#pragma unroll
    for (int ks = 0; ks < 4; ++ks) {
        const int kc = ks * 4 + lq;
#pragma unroll
        for (int nt = 0; nt < 4; ++nt) {
            const bf16x8 b = frag_ld(xb, nt * 16 + ln, kc);
            acc[nt] = __builtin_amdgcn_mfma_f32_16x16x32_bf16(wr_[ks], b, acc[nt], 0, 0, 0);
        }
    }
}

// 32-row strip GEMM; INIT zeroes acc
template<bool INIT>
__device__ __forceinline__ void gemmS32(const __bf16* xb, const bf16x8 wr_[4],
                                        int ln, int lq, f32x4 acc[2]) {
    if constexpr (INIT) {
        const f32x4 z = {0.f, 0.f, 0.f, 0.f};
        acc[0] = z; acc[1] = z;
    }
#pragma unroll
    for (int ks = 0; ks < 4; ++ks) {
        const int kc = ks * 4 + lq;
        const bf16x8 b0 = frag_ld(xb, ln, kc);
        const bf16x8 b1 = frag_ld(xb, 16 + ln, kc);
        acc[0] = __builtin_amdgcn_mfma_f32_16x16x32_bf16(wr_[ks], b0, acc[0], 0, 0, 0);
        acc[1] = __builtin_amdgcn_mfma_f32_16x16x32_bf16(wr_[ks], b1, acc[1], 0, 0, 0);
    }
}

// 64-row epilogue -> swizzled LDS
template<int ACT>
__device__ __forceinline__ void epiS64_lds(const f32x4 acc[4], __bf16* dst,
                                           const float* __restrict__ bias,
                                           int wst, int ln, int lq) {
    const int cb = wst * 16 + lq * 4;
    const f32x4 bv = *(const f32x4*)&bias[cb];
#pragma unroll
    for (int nt = 0; nt < 4; ++nt) {
        const int jr = nt * 16 + ln;
        bf16x4 o;
#pragma unroll
        for (int r = 0; r < 4; ++r)
            o[r] = (__bf16)apply_act<ACT>(acc[nt][r] + bv[r]);
        *(bf16x4*)&dst[jr * D_ + (((cb >> 3) ^ (jr & 7)) << 3) + (cb & 7)] = o;
    }
}

// 32-row epilogue -> swizzled LDS at row offset
template<int ACT>
__device__ __forceinline__ void epiS32_lds(const f32x4 acc[2], __bf16* dst, int rowoff,
                                           const float* __restrict__ bias,
                                           int wst, int ln, int lq) {
    const int cb = wst * 16 + lq * 4;
    const f32x4 bv = *(const f32x4*)&bias[cb];
#pragma unroll
    for (int nt = 0; nt < 2; ++nt) {
        const int jr = rowoff + nt * 16 + ln;
        bf16x4 o;
#pragma unroll
        for (int r = 0; r < 4; ++r)
            o[r] = (__bf16)apply_act<ACT>(acc[nt][r] + bv[r]);
        *(bf16x4*)&dst[jr * D_ + (((cb >> 3) ^ (jr & 7)) << 3) + (cb & 7)] = o;
    }
}

// prep: blocks 0-5 convert W fp32 -> WT bf16 swizzled; blocks 6-69 Sbuf + nvalid
__global__ __launch_bounds__(256) void k_prep(
    const float* __restrict__ w0, const float* __restrict__ w1,
    const float* __restrict__ w2, const float* __restrict__ w3,
    const float* __restrict__ w4, const float* __restrict__ w5,
    __bf16* __restrict__ wdst,
    const float* __restrict__ F, const int* __restrict__ STEP,
    const int* __restrict__ ENDB, const int* __restrict__ BIDX,
    float* __restrict__ Sbuf, int* __restrict__ nvalid) {
    const int t = threadIdx.x;
    if (blockIdx.x < 6) {
        const float* src;
        switch (blockIdx.x) {
            case 0: src = w0; break; case 1: src = w1; break; case 2: src = w2; break;
            case 3: src = w3; break; case 4: src = w4; break; default: src = w5; break;
        }
        __bf16* d = wdst + (size_t)blockIdx.x * D_ * D_;
        for (int id = t; id < D_ * 16; id += 256) {
            const int n = id >> 4, ch = id & 15;
            bf16x8 u;
#pragma unroll
            for (int j = 0; j < 8; ++j) u[j] = (__bf16)src[(ch * 8 + j) * D_ + n];
            *(bf16x8*)&d[n * D_ + ((ch ^ (n & 7)) << 3)] = u;
        }
        return;
    }
    const int b = blockIdx.x - 6;
    __shared__ int steps_s[J_];
    __shared__ int valid_s[J_];
    __shared__ int nv;
    const int bi = BIDX[b];
    if (t == 0) nv = 0;
    __syncthreads();
    if (t < J_) {
        const int s = STEP[bi * J_ + t];
        const int e = ENDB[bi * J_ + t];
        steps_s[t] = s;
        const int v = (s <= e) ? 1 : 0;
        valid_s[t] = v;
        if (v) atomicAdd(&nv, 1);
    }
    __syncthreads();
    if (t < D_) {
        float acc = 0.f;
        for (int j = 0; j < J_; ++j)
            if (valid_s[j]) acc += F[((size_t)b * N_ + steps_s[j]) * D_ + t];
        Sbuf[b * D_ + t] = acc;
    }
    if (t == 0) nvalid[b] = nv;
}

// fully fused, 32-output-row blocks, 512 threads (8 waves x 16-col strips), 32 KB LDS.
// R22 kernel + XCD-aware block swizzle (nwg=4096 divisible by 8 -> bijective).
__global__ __launch_bounds__(512, 4) void k_fused(
    const float* __restrict__ F, const float* __restrict__ rp_,
    const __bf16* __restrict__ wsW,
    const float* __restrict__ fb1, const float* __restrict__ fb2,
    const float* __restrict__ zb1, const float* __restrict__ zb2,
    const float* __restrict__ pb1, const float* __restrict__ pb2,
    const int* __restrict__ STEP, const int* __restrict__ ENDB,
    const int* __restrict__ BIDX, const float* __restrict__ Sbuf,
    const int* __restrict__ nvalid, float* __restrict__ out) {
    __shared__ __bf16 xs[64 * D_];   // rows 0-31: x -> cand/z (predicated); rows 32-63: xprev
    __shared__ __bf16 hs[64 * D_];   // fw h; head: mixed/zh; pr: h'

    const int t = threadIdx.x;
    const int lane = t & 63, wst = t >> 6;        // wst 0..7, 16-col strip
    const int ln = lane & 15, lq = lane >> 4;
    // XCD swizzle: consecutive logical tiles land on the same XCD's L2
    const int bid = (blockIdx.x & 7) * 512 + (blockIdx.x >> 3);
    const int b = bid >> 6, ti = bid & 63;
    const int r0 = ti * 32;
    const int bi = BIDX[b];
    const int jb = ti >> 1;                        // the single job covering rows [r0, r0+31]
    const int s_j = STEP[bi * J_ + jb];
    const int e_j = ENDB[bi * J_ + jb];
    const float r = *rp_;
    const float l2r = __log2f(r);
    const int lo = (s_j + 1 > r0) ? s_j + 1 : r0;
    const int hi = (e_j < r0 + 31) ? e_j : r0 + 31;
    const bool has_upd = lo <= hi;
    const bool head_tile = (ti == 0);

    // ---- stage: one chunk per thread per half (512 = 32 rows x 16 chunks) ----
    const float* Fb = F + (size_t)b * N_ * D_;
    const int rr_ = t >> 4;            // 0..31
    const int ch_ = t & 15;
    const int rA = r0 + rr_;
    const float* qA = Fb + (size_t)rA * D_ + ch_ * 8;
    const float4 xa0 = *(const float4*)qA, xa1 = *(const float4*)(qA + 4);
    float4 ya0, ya1;
    float scA = 0.f;
    if (has_upd) {
        const bool uA = (rA > s_j) && (rA <= e_j);
        scA = uA ? exp2f((float)(rA - s_j) * l2r) : 0.f;
        const float* uqA = Fb + (size_t)(uA ? rA - 1 : rA) * D_ + ch_ * 8;
        ya0 = *(const float4*)uqA; ya1 = *(const float4*)(uqA + 4);
    }
    // prefetch first W strip: fw W1 (has_upd) else pr P1
    bf16x8 wA[4];
    load_wregs1(has_upd ? wsW : wsW + 2 * 16384, wst, ln, lq, wA);

    st_row(xs, rr_, ch_, xa0, xa1, 1.f);
    if (has_upd) st_row(xs, rr_ + 32, ch_, ya0, ya1, scA);
    __syncthreads();                         // (1) staging visible

    if (has_upd) {
        // fw layer 1: both branches in one 64-row GEMM -> hs; W2 prefetch under epi
        f32x4 acc[4];
        gemmS64(xs, wA, ln, lq, acc);
        bf16x8 wB[4];
        load_wregs1(wsW + 16384, wst, ln, lq, wB);    // fw W2^T strip (in flight)
        epiS64_lds<ACT_ELU>(acc, hs, fb1, wst, ln, lq);
        __syncthreads();                     // (2) h visible
        // fw layer 2: chain both h halves -> cand, predicated into xs rows 0-31
        f32x4 a2[2];
        gemmS32<true>(hs, wB, ln, lq, a2);
        gemmS32<false>(hs + 32 * D_, wB, ln, lq, a2);
        const int cb = wst * 16 + lq * 4;
        const f32x4 bv = *(const f32x4*)&fb2[cb];
#pragma unroll
        for (int nt = 0; nt < 2; ++nt) {
            const int row = nt * 16 + ln;
            const int i = r0 + row;
            if (!((i > s_j) && (i <= e_j))) continue;
            bf16x4 o;
#pragma unroll
            for (int rr2 = 0; rr2 < 4; ++rr2)
                o[rr2] = (__bf16)(a2[nt][rr2] + 2.f * bv[rr2]);
            *(bf16x4*)&xs[row * D_ + (((cb >> 3) ^ (row & 7)) << 3) + (cb & 7)] = o;
        }
    }

    // head path (tile 0 of each batch): z = MLP_zj(mixed) -> xs rows 0-31 (valid jobs)
    if (head_tile) {
        __syncthreads();                     // fw2 hs reads + cand xs writes done
        const float n_ = (float)nvalid[b];
        const float inv = (n_ > 0.f) ? 1.f / n_ : 0.f;
        {
            const int row = t >> 4, ch = t & 15;  // 512 = 32 rows x 16 chunks
            const int sr = STEP[bi * J_ + row];
            const float* cr = Fb + (size_t)sr * D_ + ch * 8;
            const float4 c0 = *(const float4*)cr, c1 = *(const float4*)(cr + 4);
            const float4 s0 = *(const float4*)(Sbuf + b * D_ + ch * 8);
            const float4 s1 = *(const float4*)(Sbuf + b * D_ + ch * 8 + 4);
            bf16x8 u;
            u[0] = (__bf16)((c0.x + r * (s0.x - c0.x)) * inv);
            u[1] = (__bf16)((c0.y + r * (s0.y - c0.y)) * inv);
            u[2] = (__bf16)((c0.z + r * (s0.z - c0.z)) * inv);
            u[3] = (__bf16)((c0.w + r * (s0.w - c0.w)) * inv);
            u[4] = (__bf16)((c1.x + r * (s1.x - c1.x)) * inv);
            u[5] = (__bf16)((c1.y + r * (s1.y - c1.y)) * inv);
            u[6] = (__bf16)((c1.z + r * (s1.z - c1.z)) * inv);
            u[7] = (__bf16)((c1.w + r * (s1.w - c1.w)) * inv);
            *(bf16x8*)&hs[row * D_ + ((ch ^ (row & 7)) << 3)] = u;
        }
        __syncthreads();                     // mixed visible
        {
            bf16x8 wza[4];
            load_wregs1(wsW + 4 * 16384, wst, ln, lq, wza);
            f32x4 az[2];
            gemmS32<true>(hs, wza, ln, lq, az);                 // reads hs rows 0-31
            epiS32_lds<ACT_ELU>(az, hs, 32, zb1, wst, ln, lq);  // writes rows 32-63 (disjoint)
        }
        __syncthreads();                     // zh visible
        {
            bf16x8 wzb[4];
            load_wregs1(wsW + 5 * 16384, wst, ln, lq, wzb);
            f32x4 az[2];
            gemmS32<true>(hs + 32 * D_, wzb, ln, lq, az);
            const int cb = wst * 16 + lq * 4;
            const f32x4 bv = *(const f32x4*)&zb2[cb];
#pragma unroll
            for (int nt = 0; nt < 2; ++nt) {
                const int row = nt * 16 + ln;
                const int sr = STEP[bi * J_ + row];
                const int er = ENDB[bi * J_ + row];
                if (sr > er) continue;       // invalid job -> keep x/cand
                bf16x4 o;
#pragma unroll
                for (int rr2 = 0; rr2 < 4; ++rr2)
                    o[rr2] = (__bf16)(az[nt][rr2] + bv[rr2]);
                *(bf16x4*)&xs[row * D_ + (((cb >> 3) ^ (row & 7)) << 3) + (cb & 7)] = o;
            }
        }
    }

    // For tiles that ran fw/head: reload wA <- pr P1 and fence xs writes.
    // Pure passthrough tiles skip both (xs untouched since staging barrier).
    if (has_upd || head_tile) {
        load_wregs1(wsW + 2 * 16384, wst, ln, lq, wA);
        __syncthreads();                     // xs final (x/cand/z); hs free
    }

    // pr layer 1: xs rows 0-31 -> h' -> hs rows 0-31; P2 prefetch under epi
    f32x4 ap[2];
    gemmS32<true>(xs, wA, ln, lq, ap);
    bf16x8 wB2[4];
    load_wregs1(wsW + 3 * 16384, wst, ln, lq, wB2);   // pr P2^T strip (in flight)
    epiS32_lds<ACT_ELU>(ap, hs, 0, pb1, wst, ln, lq);
    __syncthreads();                         // h' visible

    // pr layer 2: hs rows 0-31 -> out
    gemmS32<true>(hs, wB2, ln, lq, ap);
    float* outb = out + ((size_t)b * N_ + r0) * D_;
    const int cb = wst * 16 + lq * 4;
    const f32x4 bv = *(const f32x4*)&pb2[cb];
#pragma unroll
    for (int nt = 0; nt < 2; ++nt) {
        const int jr = nt * 16 + ln;
        f32x4 o;
#pragma unroll
        for (int rr2 = 0; rr2 < 4; ++rr2)
            o[rr2] = apply_act<ACT_LEAKY>(ap[nt][rr2] + bv[rr2]);
        *(f32x4*)&outb[(size_t)jr * D_ + cb] = o;
    }
}

extern "C" void kernel_launch(void* const* d_in, const int* in_sizes, int n_in,
                              void* d_out, int out_size, void* d_ws, size_t ws_size,
                              hipStream_t stream) {
    const float* F    = (const float*)d_in[0];
    const float* rp   = (const float*)d_in[1];
    const int*  STEP  = (const int*)d_in[2];
    const int*  ENDB  = (const int*)d_in[3];
    const int*  BIDX  = (const int*)d_in[5];
    const float* fwW1 = (const float*)d_in[6];
    const float* fwb1 = (const float*)d_in[7];
    const float* fwW2 = (const float*)d_in[8];
    const float* fwb2 = (const float*)d_in[9];
    const float* zjW1 = (const float*)d_in[10];
    const float* zjb1 = (const float*)d_in[11];
    const float* zjW2 = (const float*)d_in[12];
    const float* zjb2 = (const float*)d_in[13];
    const float* prW1 = (const float*)d_in[14];
    const float* prb1 = (const float*)d_in[15];
    const float* prW2 = (const float*)d_in[16];
    const float* prb2 = (const float*)d_in[17];
    float* out = (float*)d_out;

    char* ws = (char*)d_ws;
    __bf16* wsW = (__bf16*)ws;                 // 393216 B
    float* Sbuf = (float*)(ws + 393216);       // 32768 B
    int* nvalid = (int*)(ws + 425984);         // 256 B

    hipLaunchKernelGGL(k_prep, dim3(70), dim3(256), 0, stream,
                       fwW1, fwW2, prW1, prW2, zjW1, zjW2, wsW,
                       F, STEP, ENDB, BIDX, Sbuf, nvalid);
    hipLaunchKernelGGL(k_fused, dim3(B_ * 64), dim3(512), 0, stream,
                       F, rp, wsW, fwb1, fwb2, zjb1, zjb2, prb1, prb2,
                       STEP, ENDB, BIDX, Sbuf, nvalid, out);
}